// Round 1
// baseline (329.210 us; speedup 1.0000x reference)
//
#include <hip/hip_runtime.h>
#include <cstdint>

// SNN (2-layer LIF, 10 timesteps) — one thread per batch element.
// Bit-exact JAX emulation:
//  - threefry2x32-20, key = (0, 42)  [jax.random.key(42)]
//  - partitionable random_bits (JAX >= 0.4.36 default): counter = elem index
//    (hi=0, lo=idx), 32-bit output = out0 ^ out1
//  - uniform: bitcast((bits>>9)|0x3f800000) - 1.0f
//  - LIF elementwise ops with explicit single-rounded intrinsics (no contraction)
//  - dots as ascending fma chains from 0, then (i_dec + dot_in) + dot_rec

__device__ __forceinline__ uint32_t rotl32(uint32_t x, int r) {
  return (x << r) | (x >> (32 - r));
}

__device__ __forceinline__ uint32_t threefry_xor(uint32_t x0, uint32_t x1) {
  constexpr uint32_t K0 = 0u;
  constexpr uint32_t K1 = 42u;
  constexpr uint32_t K2 = 0x1BD11BDAu ^ K0 ^ K1;
  x0 += K0; x1 += K1;
#define TF_RND(r) { x0 += x1; x1 = rotl32(x1, (r)); x1 ^= x0; }
  TF_RND(13) TF_RND(15) TF_RND(26) TF_RND(6)
  x0 += K1; x1 += K2 + 1u;
  TF_RND(17) TF_RND(29) TF_RND(16) TF_RND(24)
  x0 += K2; x1 += K0 + 2u;
  TF_RND(13) TF_RND(15) TF_RND(26) TF_RND(6)
  x0 += K0; x1 += K1 + 3u;
  TF_RND(17) TF_RND(29) TF_RND(16) TF_RND(24)
  x0 += K1; x1 += K2 + 4u;
  TF_RND(13) TF_RND(15) TF_RND(26) TF_RND(6)
  x0 += K2; x1 += K0 + 5u;
#undef TF_RND
  return x0 ^ x1;
}

__global__ __launch_bounds__(256) void snn_kernel(
    const float* __restrict__ x_in, const float* __restrict__ w_in0,
    const float* __restrict__ w_rec0, const float* __restrict__ w_in1,
    const float* __restrict__ w_rec1, float* __restrict__ out, int B)
{
  int b = blockIdx.x * blockDim.x + threadIdx.x;
  if (b >= B) return;

  // ---- inputs (rates), 48B aligned per row -> 3x float4 ----
  float x[12];
  {
    const float4* xv = reinterpret_cast<const float4*>(x_in + (size_t)b * 12);
    float4 q0 = xv[0], q1 = xv[1], q2 = xv[2];
    x[0]=q0.x; x[1]=q0.y; x[2]=q0.z;  x[3]=q0.w;
    x[4]=q1.x; x[5]=q1.y; x[6]=q1.z;  x[7]=q1.w;
    x[8]=q2.x; x[9]=q2.y; x[10]=q2.z; x[11]=q2.w;
  }

  // ---- weights (uniform across threads -> scalar loads) ----
  float W0[6][12], R0[6][6], W1[6], R1;
  #pragma unroll
  for (int n = 0; n < 6; ++n) {
    #pragma unroll
    for (int j = 0; j < 12; ++j) W0[n][j] = w_in0[n * 12 + j];
  }
  #pragma unroll
  for (int n = 0; n < 6; ++n) {
    #pragma unroll
    for (int j = 0; j < 6; ++j) R0[n][j] = w_rec0[n * 6 + j];
  }
  #pragma unroll
  for (int j = 0; j < 6; ++j) W1[j] = w_in1[j];
  R1 = w_rec1[0];

  // ---- state ----
  float v0[6], i0[6], z0[6];
  #pragma unroll
  for (int n = 0; n < 6; ++n) { v0[n] = 0.0f; i0[n] = 0.0f; z0[n] = 0.0f; }
  float v1 = 0.0f, i1 = 0.0f, z1 = 0.0f;

  const uint32_t t_stride = (uint32_t)B * 12u;
  const uint32_t base_b = (uint32_t)b * 12u;

  for (int t = 0; t < 10; ++t) {
    // ---- Poisson spikes for this timestep (bit-exact JAX uniform) ----
    const uint32_t base = (uint32_t)t * t_stride + base_b;
    float sp[12];
    #pragma unroll
    for (int j = 0; j < 12; ++j) {
      uint32_t bits = threefry_xor(0u, base + (uint32_t)j);
      float u = __fsub_rn(__uint_as_float((bits >> 9) | 0x3f800000u), 1.0f);
      sp[j] = (u < x[j]) ? 1.0f : 0.0f;
    }

    // ---- layer 0: 6 LIF neurons ----
    float zn[6], vn[6], inew[6];
    #pragma unroll
    for (int n = 0; n < 6; ++n) {
      float vdec = __fadd_rn(v0[n], __fmul_rn(0.1f, __fsub_rn(i0[n], v0[n])));
      float idec = __fsub_rn(i0[n], __fmul_rn(0.2f, i0[n]));
      bool fire = (vdec > 1.0f);          // == (vdec - 1.0f) > 0, exactly
      zn[n] = fire ? 1.0f : 0.0f;
      vn[n] = fire ? 0.0f : vdec;
      float d1 = 0.0f;
      #pragma unroll
      for (int j = 0; j < 12; ++j) d1 = __fmaf_rn(sp[j], W0[n][j], d1);
      float d2 = 0.0f;
      #pragma unroll
      for (int j = 0; j < 6; ++j) d2 = __fmaf_rn(z0[j], R0[n][j], d2);
      inew[n] = __fadd_rn(__fadd_rn(idec, d1), d2);
    }

    // ---- layer 1: 1 LIF neuron (input = NEW z0, recurrence = OLD z1) ----
    {
      float vdec = __fadd_rn(v1, __fmul_rn(0.1f, __fsub_rn(i1, v1)));
      float idec = __fsub_rn(i1, __fmul_rn(0.2f, i1));
      bool fire = (vdec > 1.0f);
      float z1n = fire ? 1.0f : 0.0f;
      float v1n = fire ? 0.0f : vdec;
      float d1 = 0.0f;
      #pragma unroll
      for (int j = 0; j < 6; ++j) d1 = __fmaf_rn(zn[j], W1[j], d1);
      float d2 = __fmaf_rn(z1, R1, 0.0f);  // K=1 dot
      float i1n = __fadd_rn(__fadd_rn(idec, d1), d2);
      z1 = z1n; v1 = v1n; i1 = i1n;
    }

    // ---- commit layer-0 state ----
    #pragma unroll
    for (int n = 0; n < 6; ++n) { z0[n] = zn[n]; v0[n] = vn[n]; i0[n] = inew[n]; }
  }

  out[b] = z1;  // final-timestep output spike
}

extern "C" void kernel_launch(void* const* d_in, const int* in_sizes, int n_in,
                              void* d_out, int out_size, void* d_ws, size_t ws_size,
                              hipStream_t stream) {
  const float* x      = (const float*)d_in[0];   // [B,12]
  const float* w_in0  = (const float*)d_in[1];   // [6,12]
  const float* w_rec0 = (const float*)d_in[2];   // [6,6]
  const float* w_in1  = (const float*)d_in[3];   // [1,6]
  const float* w_rec1 = (const float*)d_in[4];   // [1,1]
  float* out = (float*)d_out;                    // [B,1]

  const int B = out_size;                        // 1048576
  const int block = 256;
  const int grid = (B + block - 1) / block;
  snn_kernel<<<grid, block, 0, stream>>>(x, w_in0, w_rec0, w_in1, w_rec1, out, B);
}

// Round 2
// 284.290 us; speedup vs baseline: 1.1580x; 1.1580x over previous
//
#include <hip/hip_runtime.h>
#include <cstdint>

// SNN (2-layer LIF, 10 timesteps) — one thread per batch element.
// Bit-exact JAX emulation (verified absmax=0 in R1):
//  - threefry2x32-20, key=(0,42), partitionable counter mode, out = x0^x1
//  - uniform compare done in INTEGER domain: u = (bits>>9)*2^-23 exactly, so
//    u < x  <=>  (bits>>9) < ceil(x*2^23)   [x in [0,1), scale by 2^23 exact]
//  - rotates forced to v_alignbit_b32 (1 VALU op) via builtin
//  - LIF elementwise ops with explicit single-rounded intrinsics
//  - dots as ascending fma chains from 0, then (i_dec + dot_in) + dot_rec

#define TFR(r) { x0 += x1; x1 = __builtin_amdgcn_alignbit(x1, x1, 32 - (r)); x1 ^= x0; }

__device__ __forceinline__ uint32_t tf_hash(uint32_t c) {
  // key (0,42): ks0=0, ks1=42, ks2=0x1BD11BDA^42=0x1BD11BF0
  uint32_t x0 = 0u;
  uint32_t x1 = c + 42u;                   // c + ks1
  TFR(13) TFR(15) TFR(26) TFR(6)
  x0 += 42u;          x1 += 0x1BD11BF1u;   // ks1, ks2+1
  TFR(17) TFR(29) TFR(16) TFR(24)
  x0 += 0x1BD11BF0u;  x1 += 2u;            // ks2, ks0+2
  TFR(13) TFR(15) TFR(26) TFR(6)
  /* x0 += 0 */       x1 += 45u;           // ks0, ks1+3
  TFR(17) TFR(29) TFR(16) TFR(24)
  x0 += 42u;          x1 += 0x1BD11BF4u;   // ks1, ks2+4
  TFR(13) TFR(15) TFR(26) TFR(6)
  x0 += 0x1BD11BF0u;  x1 += 5u;            // ks2, ks0+5
  return x0 ^ x1;
}

__global__ __launch_bounds__(256) void snn_kernel(
    const float* __restrict__ x_in, const float* __restrict__ w_in0,
    const float* __restrict__ w_rec0, const float* __restrict__ w_in1,
    const float* __restrict__ w_rec1, float* __restrict__ out, int B)
{
  int b = blockIdx.x * blockDim.x + threadIdx.x;
  if (b >= B) return;

  // ---- integer spike thresholds: T[j] = ceil(x[j] * 2^23), exact ----
  uint32_t T[12];
  {
    const float4* xv = reinterpret_cast<const float4*>(x_in + (size_t)b * 12);
    float4 q0 = xv[0], q1 = xv[1], q2 = xv[2];
    float x[12] = {q0.x,q0.y,q0.z,q0.w, q1.x,q1.y,q1.z,q1.w, q2.x,q2.y,q2.z,q2.w};
    #pragma unroll
    for (int j = 0; j < 12; ++j)
      T[j] = (uint32_t)__builtin_ceilf(x[j] * 8388608.0f);
  }

  // ---- weights (wave-uniform -> scalar loads) ----
  float W0[6][12], R0[6][6], W1[6], R1;
  #pragma unroll
  for (int n = 0; n < 6; ++n) {
    #pragma unroll
    for (int j = 0; j < 12; ++j) W0[n][j] = w_in0[n * 12 + j];
  }
  #pragma unroll
  for (int n = 0; n < 6; ++n) {
    #pragma unroll
    for (int j = 0; j < 6; ++j) R0[n][j] = w_rec0[n * 6 + j];
  }
  #pragma unroll
  for (int j = 0; j < 6; ++j) W1[j] = w_in1[j];
  R1 = w_rec1[0];

  // ---- state ----
  float v0[6], i0[6], z0[6];
  #pragma unroll
  for (int n = 0; n < 6; ++n) { v0[n] = 0.0f; i0[n] = 0.0f; z0[n] = 0.0f; }
  float v1 = 0.0f, i1 = 0.0f, z1 = 0.0f;

  const uint32_t t_stride = (uint32_t)B * 12u;
  uint32_t base = (uint32_t)b * 12u;   // counter for (t, b, 0); += t_stride per step

  #pragma unroll
  for (int t = 0; t < 10; ++t) {
    // ---- Poisson spikes (integer-domain compare, bit-exact) ----
    float sp[12];
    #pragma unroll
    for (int j = 0; j < 12; ++j) {
      uint32_t h = tf_hash(base + (uint32_t)j);
      sp[j] = ((h >> 9) < T[j]) ? 1.0f : 0.0f;
    }
    base += t_stride;

    // ---- layer 0: 6 LIF neurons ----
    float zn[6], vn[6], inew[6];
    #pragma unroll
    for (int n = 0; n < 6; ++n) {
      float vdec = __fadd_rn(v0[n], __fmul_rn(0.1f, __fsub_rn(i0[n], v0[n])));
      float idec = __fsub_rn(i0[n], __fmul_rn(0.2f, i0[n]));
      bool fire = (vdec > 1.0f);          // == (vdec - 1.0f) > 0, exactly
      zn[n] = fire ? 1.0f : 0.0f;
      vn[n] = fire ? 0.0f : vdec;
      float d1 = 0.0f;
      #pragma unroll
      for (int j = 0; j < 12; ++j) d1 = __fmaf_rn(sp[j], W0[n][j], d1);
      float d2 = 0.0f;
      #pragma unroll
      for (int j = 0; j < 6; ++j) d2 = __fmaf_rn(z0[j], R0[n][j], d2);
      inew[n] = __fadd_rn(__fadd_rn(idec, d1), d2);
    }

    // ---- layer 1: 1 LIF neuron (input = NEW z0, recurrence = OLD z1) ----
    {
      float vdec = __fadd_rn(v1, __fmul_rn(0.1f, __fsub_rn(i1, v1)));
      float idec = __fsub_rn(i1, __fmul_rn(0.2f, i1));
      bool fire = (vdec > 1.0f);
      float z1n = fire ? 1.0f : 0.0f;
      float v1n = fire ? 0.0f : vdec;
      float d1 = 0.0f;
      #pragma unroll
      for (int j = 0; j < 6; ++j) d1 = __fmaf_rn(zn[j], W1[j], d1);
      float d2 = __fmaf_rn(z1, R1, 0.0f);  // K=1 dot
      float i1n = __fadd_rn(__fadd_rn(idec, d1), d2);
      z1 = z1n; v1 = v1n; i1 = i1n;
    }

    // ---- commit layer-0 state ----
    #pragma unroll
    for (int n = 0; n < 6; ++n) { z0[n] = zn[n]; v0[n] = vn[n]; i0[n] = inew[n]; }
  }

  out[b] = z1;  // final-timestep output spike
}

extern "C" void kernel_launch(void* const* d_in, const int* in_sizes, int n_in,
                              void* d_out, int out_size, void* d_ws, size_t ws_size,
                              hipStream_t stream) {
  const float* x      = (const float*)d_in[0];   // [B,12]
  const float* w_in0  = (const float*)d_in[1];   // [6,12]
  const float* w_rec0 = (const float*)d_in[2];   // [6,6]
  const float* w_in1  = (const float*)d_in[3];   // [1,6]
  const float* w_rec1 = (const float*)d_in[4];   // [1,1]
  float* out = (float*)d_out;                    // [B,1]

  const int B = out_size;                        // 1048576
  const int block = 256;
  const int grid = (B + block - 1) / block;
  snn_kernel<<<grid, block, 0, stream>>>(x, w_in0, w_rec0, w_in1, w_rec1, out, B);
}